// Round 2
// baseline (2586.539 us; speedup 1.0000x reference)
//
#include <hip/hip_runtime.h>
#include <math.h>

// Problem constants
#define B_ 8
#define T_ 64
#define N_ 197
#define D_ 768
#define HIDD_ 3072   // HID*D
#define KF_ 8
#define KT_ 49

// Output layout (floats, concatenated in reference return order)
#define Z_SZ    (B_*KF_*KT_*D_)       // 2408448
#define FI_OFF  (Z_SZ)                // 2408448
#define FI_SZ   (B_*KF_)              // 64
#define TI_OFF  (FI_OFF + FI_SZ)      // 2408512
#define TI_SZ   (B_*KF_*KT_)          // 3136
#define FM_OFF  (TI_OFF + TI_SZ)      // 2411648
#define FM_SZ   (B_*T_)               // 512
#define TM_OFF  (FM_OFF + FM_SZ)      // 2412160

// Workspace layout (bytes)
#define WS_SCORE   0                          // 512 doubles = 4096
#define WS_FN64    4096                       // 512*768 doubles = 3145728
#define WS_H32     (4096 + 3145728)           // 512*768 floats = 1572864
#define WS_VALID   (WS_H32 + 1572864)         // 512 ints = 2048
#define WS_FIDX    (WS_VALID + 2048)          // 64 ints (pad to 256)
#define WS_TOK     (WS_FIDX + 256)            // 3136 ints = 12544

// ---------------------------------------------------------------------------
// Kernel A: masked-mean frame_repr (fp64), LayerNorm -> h32 (GEMM input),
// L2-normalized fn64 (for cosine sim), valid flags.
// One block per (b,t) row. 256 threads; threads 0..191 each own 4 consecutive
// dims (float4 loads, 3 KB contiguous per n-step).
// ---------------------------------------------------------------------------
__global__ __launch_bounds__(256) void kA(const float* __restrict__ x,
                                          const float* __restrict__ mask,
                                          const float* __restrict__ gamma,
                                          const float* __restrict__ beta,
                                          double* __restrict__ fn64,
                                          float* __restrict__ h32,
                                          int* __restrict__ validw) {
  const int row = blockIdx.x;          // b*T + t
  const int tid = threadIdx.x;
  __shared__ float  ms[N_];
  __shared__ double red[256];
  __shared__ double sh_denom, sh_mu, sh_sd, sh_nrm;
  const float* xr = x + (size_t)row * (N_ * D_);

  if (tid < N_) ms[tid] = mask[(size_t)row * N_ + tid];
  __syncthreads();

  // denom = clip(sum(mask), 1e-6)
  red[tid] = (tid < N_) ? (double)ms[tid] : 0.0;
  __syncthreads();
  for (int s = 128; s > 0; s >>= 1) { if (tid < s) red[tid] += red[tid + s]; __syncthreads(); }
  if (tid == 0) { double d = red[0]; sh_denom = (d > 1e-6) ? d : 1e-6; }
  __syncthreads();
  const double dn = sh_denom;

  // masked mean over n (fp64 accumulate), float4 vector loads
  double a0 = 0.0, a1 = 0.0, a2 = 0.0, a3 = 0.0;
  if (tid < 192) {
    const float* px = xr + tid * 4;
#pragma unroll 4
    for (int n = 0; n < N_; n++) {
      const double mv = (double)ms[n];
      const float4 v = *(const float4*)(px + (size_t)n * D_);
      a0 += (double)v.x * mv;
      a1 += (double)v.y * mv;
      a2 += (double)v.z * mv;
      a3 += (double)v.w * mv;
    }
  }
  const double f0 = a0 / dn, f1 = a1 / dn, f2 = a2 / dn, f3 = a3 / dn;

  // mean
  red[tid] = (tid < 192) ? (f0 + f1 + f2 + f3) : 0.0; __syncthreads();
  for (int s = 128; s > 0; s >>= 1) { if (tid < s) red[tid] += red[tid + s]; __syncthreads(); }
  if (tid == 0) sh_mu = red[0] / (double)D_;
  __syncthreads();
  const double mu = sh_mu;

  // L2 norm of frame_repr (for cosine normalize, eps 1e-12)
  red[tid] = (tid < 192) ? (f0 * f0 + f1 * f1 + f2 * f2 + f3 * f3) : 0.0; __syncthreads();
  for (int s = 128; s > 0; s >>= 1) { if (tid < s) red[tid] += red[tid + s]; __syncthreads(); }
  if (tid == 0) { double nr = sqrt(red[0]); sh_nrm = (nr > 1e-12) ? nr : 1e-12; }
  __syncthreads();

  // variance (direct (x-mu)^2 mean, faithful to reference)
  red[tid] = (tid < 192) ? ((f0 - mu) * (f0 - mu) + (f1 - mu) * (f1 - mu) +
                            (f2 - mu) * (f2 - mu) + (f3 - mu) * (f3 - mu)) : 0.0;
  __syncthreads();
  for (int s = 128; s > 0; s >>= 1) { if (tid < s) red[tid] += red[tid + s]; __syncthreads(); }
  if (tid == 0) sh_sd = sqrt(red[0] / (double)D_ + 1e-5);
  __syncthreads();
  const double sd = sh_sd, nrm = sh_nrm;

  if (tid < 192) {
    const size_t base = (size_t)row * D_;
    const float4 g  = ((const float4*)gamma)[tid];
    const float4 be = ((const float4*)beta)[tid];
    float4 hv;
    hv.x = (float)((f0 - mu) / sd * (double)g.x + (double)be.x);
    hv.y = (float)((f1 - mu) / sd * (double)g.y + (double)be.y);
    hv.z = (float)((f2 - mu) / sd * (double)g.z + (double)be.z);
    hv.w = (float)((f3 - mu) / sd * (double)g.w + (double)be.w);
    *(float4*)(h32 + base + tid * 4) = hv;
    double2* fp = (double2*)(fn64 + base + tid * 4);
    fp[0] = make_double2(f0 / nrm, f1 / nrm);
    fp[1] = make_double2(f2 / nrm, f3 / nrm);
  }
  if (tid == 0) validw[row] = 1;  // clip(denom,1e-6) > 0 is always true
}

// ---------------------------------------------------------------------------
// Kernel B: score = gelu(h @ W1 + b1) @ W2, fused (no h1 materialization).
// Tiled fp32 GEMM, M=512 N=3072 K=768; Mtile=32, Ntile=128, BK=64,
// 256 threads with 4x4 micro-tiles; fp64 GELU/W2 epilogue + fp64 atomicAdd.
// Grid: (3072/128=24, 512/32=16).
// ---------------------------------------------------------------------------
__global__ __launch_bounds__(256) void kB(const float* __restrict__ h32,
                                          const float* __restrict__ W1,
                                          const float* __restrict__ b1,
                                          const float* __restrict__ W2,
                                          double* __restrict__ score) {
  const int n0 = blockIdx.x * 128;
  const int m0 = blockIdx.y * 32;
  const int tid = threadIdx.x;
  const int tx = tid & 31;   // 32 col-groups of 4
  const int ty = tid >> 5;   // 8 row-groups of 4
  __shared__ float As[64 * 33];   // [k][m], padded
  __shared__ float Bs[64 * 128];  // [k][n]
  float acc[4][4];
#pragma unroll
  for (int r = 0; r < 4; r++)
#pragma unroll
    for (int c = 0; c < 4; c++) acc[r][c] = 0.0f;

  for (int kc = 0; kc < 12; kc++) {
    const int k0 = kc * 64;
#pragma unroll
    for (int it = 0; it < 8; it++) {           // A: 32x64 = 2048 floats
      int idx = tid + (it << 8);
      int k = idx & 63, m = idx >> 6;
      As[k * 33 + m] = h32[(size_t)(m0 + m) * D_ + k0 + k];
    }
#pragma unroll
    for (int it = 0; it < 8; it++) {           // B: 64x128 = 2048 float4
      int idx = tid + (it << 8);
      int k = idx >> 5, n4 = idx & 31;
      const float4 v = *(const float4*)(W1 + (size_t)(k0 + k) * HIDD_ + n0 + (n4 << 2));
      *(float4*)(Bs + k * 128 + (n4 << 2)) = v;
    }
    __syncthreads();
#pragma unroll 16
    for (int kk = 0; kk < 64; kk++) {
      float a[4], bb[4];
#pragma unroll
      for (int r = 0; r < 4; r++) a[r] = As[kk * 33 + ty * 4 + r];
#pragma unroll
      for (int c = 0; c < 4; c++) bb[c] = Bs[kk * 128 + tx * 4 + c];
#pragma unroll
      for (int r = 0; r < 4; r++)
#pragma unroll
        for (int c = 0; c < 4; c++) acc[r][c] += a[r] * bb[c];
    }
    __syncthreads();
  }

  // Epilogue: exact GELU (fp64) * W2, reduce over this block's 128 cols per row
  double part[4] = {0.0, 0.0, 0.0, 0.0};
#pragma unroll
  for (int r = 0; r < 4; r++) {
#pragma unroll
    for (int c = 0; c < 4; c++) {
      const int gn = n0 + tx * 4 + c;
      const double v = (double)(acc[r][c] + b1[gn]);
      const double g = 0.5 * v * (1.0 + erf(v * 0.7071067811865475244));
      part[r] += g * (double)W2[gn];
    }
  }
#pragma unroll
  for (int r = 0; r < 4; r++) {
    double s = part[r];
#pragma unroll
    for (int off = 16; off > 0; off >>= 1) s += __shfl_down(s, off, 32);
    if (tx == 0) atomicAdd(&score[m0 + ty * 4 + r], s);
  }
}

// ---------------------------------------------------------------------------
// Kernel D: facility-location greedy frame selection. One block per batch,
// 256 threads. sim = fn.fn^T (fp64) via 4x4 register micro-tiles (cuts LDS
// traffic 31MB -> 12.6MB/block vs 1-elem tiles). Greedy runs on wave 0.
// ---------------------------------------------------------------------------
__global__ __launch_bounds__(256) void kD(const double* __restrict__ fn64,
                                          const double* __restrict__ score,
                                          const int* __restrict__ validw,
                                          const float* __restrict__ b2,
                                          int* __restrict__ fidxw,
                                          float* __restrict__ out_fidx,
                                          float* __restrict__ out_fmask) {
  const int b = blockIdx.x;
  const int tid = threadIdx.x;
  __shared__ double fnS[64 * 65];   // chunk [t][kk], padded (33 KB)
  __shared__ double sim[64 * 64];   // 32 KB
  __shared__ double scoreS[64];
  __shared__ double bc[64];
  __shared__ int chosenS[64];
  __shared__ int validS[64];

  const int i0 = (tid >> 4) << 2;    // 0..60
  const int j0 = (tid & 15) << 2;    // 0..60
  double acc[4][4];
#pragma unroll
  for (int r = 0; r < 4; r++)
#pragma unroll
    for (int c = 0; c < 4; c++) acc[r][c] = 0.0;

  for (int c = 0; c < 12; c++) {
#pragma unroll
    for (int it = 0; it < 16; it++) {   // stage 64x64 doubles
      int idx = (it << 8) + tid;
      int t = idx >> 6, kk = idx & 63;
      fnS[t * 65 + kk] = fn64[((size_t)(b * T_ + t)) * D_ + c * 64 + kk];
    }
    __syncthreads();
#pragma unroll 4
    for (int kk = 0; kk < 64; kk++) {
      double a[4], bb[4];
#pragma unroll
      for (int r = 0; r < 4; r++) a[r] = fnS[(i0 + r) * 65 + kk];
#pragma unroll
      for (int cc = 0; cc < 4; cc++) bb[cc] = fnS[(j0 + cc) * 65 + kk];
#pragma unroll
      for (int r = 0; r < 4; r++)
#pragma unroll
        for (int cc = 0; cc < 4; cc++) acc[r][cc] += a[r] * bb[cc];
    }
    __syncthreads();
  }
#pragma unroll
  for (int r = 0; r < 4; r++)
#pragma unroll
    for (int cc = 0; cc < 4; cc++) sim[(i0 + r) * 64 + (j0 + cc)] = acc[r][cc];

  if (tid < 64) {
    scoreS[tid]  = score[b * T_ + tid] + (double)b2[0];
    validS[tid]  = validw[b * T_ + tid];
    bc[tid]      = 0.0;
    chosenS[tid] = 0;
  }
  __syncthreads();

  for (int step = 0; step < KF_; step++) {
    if (tid < 64) {
      // cov_gain(j=tid) = sum_i max(bc[i], sim[i][j]) - sum_i bc[i]
      double g = 0.0;
      for (int ii = 0; ii < 64; ii++) g += fmax(bc[ii], sim[ii * 64 + tid]);
      double bs = bc[tid];
#pragma unroll
      for (int off = 32; off > 0; off >>= 1) bs += __shfl_down(bs, off, 64);
      bs = __shfl(bs, 0, 64);
      double tot = g - bs + 0.5 * scoreS[tid];
      if (!validS[tid] || chosenS[tid]) tot = -INFINITY;
      // argmax, first-occurrence tie-break
      double bv = tot; int bi = tid;
#pragma unroll
      for (int off = 32; off > 0; off >>= 1) {
        double ov = __shfl_down(bv, off, 64);
        int    oi = __shfl_down(bi, off, 64);
        if (ov > bv || (ov == bv && oi < bi)) { bv = ov; bi = oi; }
      }
      bi = __shfl(bi, 0, 64);
      bc[tid] = fmax(bc[tid], sim[tid * 64 + bi]);
      if (tid == bi) chosenS[tid] = 1;
      if (tid == 0) {
        fidxw[b * KF_ + step] = bi;
        out_fidx[b * KF_ + step] = (float)bi;
      }
    }
    __syncthreads();
  }
  if (tid < 64) out_fmask[b * T_ + tid] = chosenS[tid] ? 1.0f : 0.0f;
}

// ---------------------------------------------------------------------------
// Kernel E: greedy k-center (farthest point sampling), one block per
// (b, selected frame). 1024 threads = 16 waves. The ENTIRE frame
// (197x768 floats) is register-cached: wave w owns rows n = w + 16*r
// (r<13), lane owns 12 dims -> 156 floats/thread. Candidate row is staged
// registers -> LDS by the owning wave (no global re-reads at all).
// All distance math fp64 (decision-exact vs numpy).
// ---------------------------------------------------------------------------
__global__ __launch_bounds__(1024) void kE(const float* __restrict__ x,
                                           const float* __restrict__ mask,
                                           const int* __restrict__ fidxw,
                                           int* __restrict__ tokw) {
  const int pair = blockIdx.x;        // b*KF + kf
  const int b = pair >> 3;
  const int tid = threadIdx.x;
  const int wave = tid >> 6;
  const int lane = tid & 63;
  const int fi = fidxw[pair];
  const float* X    = x + ((size_t)(b * T_ + fi)) * (N_ * D_);
  const float* mrow = mask + (size_t)(b * T_ + fi) * N_;

  __shared__ double md[N_];
  __shared__ float Cs[D_];
  __shared__ int validS[N_];
  __shared__ int candS;

  if (tid < N_) validS[tid] = (mrow[tid] > 0.5f) ? 1 : 0;

  // register-cache the frame
  float xreg[13][12];
#pragma unroll
  for (int r = 0; r < 13; r++) {
    const int n = wave + 16 * r;
    if (n < N_) {
      const float4* p = (const float4*)(X + (size_t)n * D_ + lane * 12);
      const float4 v0 = p[0], v1 = p[1], v2 = p[2];
      xreg[r][0] = v0.x; xreg[r][1]  = v0.y; xreg[r][2]  = v0.z; xreg[r][3]  = v0.w;
      xreg[r][4] = v1.x; xreg[r][5]  = v1.y; xreg[r][6]  = v1.z; xreg[r][7]  = v1.w;
      xreg[r][8] = v2.x; xreg[r][9]  = v2.y; xreg[r][10] = v2.z; xreg[r][11] = v2.w;
    }
  }
  __syncthreads();

  // d0 = valid ? ||X_n||^2 : -inf
#pragma unroll
  for (int r = 0; r < 13; r++) {
    const int n = wave + 16 * r;
    if (n < N_) {
      double s = 0.0;
#pragma unroll
      for (int j = 0; j < 12; j++) { const double v = (double)xreg[r][j]; s += v * v; }
#pragma unroll
      for (int off = 32; off > 0; off >>= 1) s += __shfl_down(s, off, 64);
      if (lane == 0) md[n] = validS[n] ? s : -INFINITY;
    }
  }
  __syncthreads();

  // argmax over 197 (wave 0)
  if (tid < 64) {
    double bv = md[tid]; int bi = tid;
    for (int n = tid + 64; n < N_; n += 64) {
      const double v = md[n];
      if (v > bv) { bv = v; bi = n; }
    }
#pragma unroll
    for (int off = 32; off > 0; off >>= 1) {
      const double ov = __shfl_down(bv, off, 64);
      const int    oi = __shfl_down(bi, off, 64);
      if (ov > bv || (ov == bv && oi < bi)) { bv = ov; bi = oi; }
    }
    if (tid == 0) { candS = bi; tokw[pair * KT_] = bi; }
  }
  __syncthreads();
  int cand = candS;

  for (int k = 1; k < KT_; k++) {
    // stage candidate row (registers -> LDS) by the owning wave
    if (wave == (cand & 15)) {
      const int rsel = cand >> 4;
      float c0[12];
#pragma unroll
      for (int j = 0; j < 12; j++) c0[j] = 0.0f;
#pragma unroll
      for (int r = 0; r < 13; r++) {
        if (r == rsel) {
#pragma unroll
          for (int j = 0; j < 12; j++) c0[j] = xreg[r][j];
        }
      }
#pragma unroll
      for (int j = 0; j < 12; j++) Cs[lane * 12 + j] = c0[j];
    }
    __syncthreads();

    double Cd[12];
#pragma unroll
    for (int j = 0; j < 12; j++) Cd[j] = (double)Cs[lane * 12 + j];

#pragma unroll
    for (int r = 0; r < 13; r++) {
      const int n = wave + 16 * r;
      if (n < N_) {
        double s = 0.0;
#pragma unroll
        for (int j = 0; j < 12; j++) {
          const double v = (double)xreg[r][j] - Cd[j];
          s += v * v;
        }
#pragma unroll
        for (int off = 32; off > 0; off >>= 1) s += __shfl_down(s, off, 64);
        if (lane == 0) {
          if (!validS[n]) md[n] = -1.0;
          else {
            const double dist = sqrt(s);
            md[n] = (k == 1) ? dist : fmin(md[n], dist);
          }
        }
      }
    }
    __syncthreads();

    if (tid < 64) {
      double bv = md[tid]; int bi = tid;
      for (int n = tid + 64; n < N_; n += 64) {
        const double v = md[n];
        if (v > bv) { bv = v; bi = n; }
      }
#pragma unroll
      for (int off = 32; off > 0; off >>= 1) {
        const double ov = __shfl_down(bv, off, 64);
        const int    oi = __shfl_down(bi, off, 64);
        if (ov > bv || (ov == bv && oi < bi)) { bv = ov; bi = oi; }
      }
      if (tid == 0) { candS = bi; tokw[pair * KT_ + k] = bi; }
    }
    __syncthreads();
    cand = candS;
  }
}

// ---------------------------------------------------------------------------
// Kernel F: gather z rows, write token_idx (as float), scatter token_mask.
// Wave-per-row, float4 copies. Grid 784 x 256 (4 rows per block).
// ---------------------------------------------------------------------------
__global__ __launch_bounds__(256) void kF(const float* __restrict__ x,
                                          const int* __restrict__ fidxw,
                                          const int* __restrict__ tokw,
                                          float* __restrict__ out) {
  const int row = blockIdx.x * 4 + (threadIdx.x >> 6);  // pair*KT + kt
  const int lane = threadIdx.x & 63;
  const int pair = row / KT_;
  const int b = pair >> 3;
  const int fi = fidxw[pair];
  const int tok = tokw[row];
  const float* src = x + (((size_t)(b * T_ + fi)) * N_ + tok) * D_;
  float* dst = out + (size_t)row * D_;
#pragma unroll
  for (int r = 0; r < 3; r++) {
    const int d = lane * 4 + 256 * r;
    *(float4*)(dst + d) = *(const float4*)(src + d);
  }
  if (lane == 0) {
    out[TI_OFF + row] = (float)tok;
    out[TM_OFF + (size_t)(b * T_ + fi) * N_ + tok] = 1.0f;
  }
}

// ---------------------------------------------------------------------------
extern "C" void kernel_launch(void* const* d_in, const int* in_sizes, int n_in,
                              void* d_out, int out_size, void* d_ws, size_t ws_size,
                              hipStream_t stream) {
  (void)in_sizes; (void)n_in; (void)ws_size;
  const float* x     = (const float*)d_in[0];
  const float* mask  = (const float*)d_in[1];
  const float* gamma = (const float*)d_in[2];
  const float* beta  = (const float*)d_in[3];
  const float* W1    = (const float*)d_in[4];
  const float* b1    = (const float*)d_in[5];
  const float* W2    = (const float*)d_in[6];
  const float* b2    = (const float*)d_in[7];
  float* out = (float*)d_out;
  char* ws = (char*)d_ws;

  double* score = (double*)(ws + WS_SCORE);
  double* fn64  = (double*)(ws + WS_FN64);
  float*  h32   = (float*)(ws + WS_H32);
  int*    validw = (int*)(ws + WS_VALID);
  int*    fidxw  = (int*)(ws + WS_FIDX);
  int*    tokw   = (int*)(ws + WS_TOK);

  // zero outputs (token_mask needs zeros; rest overwritten) and score accum
  hipMemsetAsync(d_out, 0, (size_t)out_size * sizeof(float), stream);
  hipMemsetAsync(score, 0, (size_t)B_ * T_ * sizeof(double), stream);

  kA<<<B_ * T_, 256, 0, stream>>>(x, mask, gamma, beta, fn64, h32, validw);
  kB<<<dim3(HIDD_ / 128, (B_ * T_) / 32), 256, 0, stream>>>(h32, W1, b1, W2, score);
  kD<<<B_, 256, 0, stream>>>(fn64, score, validw, b2, fidxw, out + FI_OFF, out + FM_OFF);
  kE<<<B_ * KF_, 1024, 0, stream>>>(x, mask, fidxw, tokw);
  kF<<<B_ * KF_ * KT_ / 4, 256, 0, stream>>>(x, fidxw, tokw, out);
}

// Round 3
// 833.305 us; speedup vs baseline: 3.1040x; 3.1040x over previous
//
#include <hip/hip_runtime.h>
#include <math.h>

// Problem constants
#define B_ 8
#define T_ 64
#define N_ 197
#define D_ 768
#define HIDD_ 3072   // HID*D
#define KF_ 8
#define KT_ 49
#define GSTRIDE 200  // padded row stride of per-pair Gram matrix (doubles)

// Output layout (floats, concatenated in reference return order)
#define Z_SZ    (B_*KF_*KT_*D_)       // 2408448
#define FI_OFF  (Z_SZ)                // 2408448
#define TI_OFF  (FI_OFF + B_*KF_)     // 2408512
#define FM_OFF  (TI_OFF + B_*KF_*KT_) // 2411648
#define TM_OFF  (FM_OFF + B_*T_)      // 2412160
#define TM_SZ   (B_*T_*N_)            // 100864

// Workspace layout (bytes)
#define WS_SCOREP  0                          // 512*24 doubles = 98304
#define WS_FN64    98304                      // 512*768*8 = 3145728
#define WS_H32     (WS_FN64 + 3145728)        // 512*768*4 = 1572864
#define WS_VALID   (WS_H32 + 1572864)         // 512*4 = 2048
#define WS_FIDX    (WS_VALID + 2048)          // 64 ints (pad 256)
#define WS_TOK     (WS_FIDX + 256)            // 3136*4 = 12544 (pad 12800)
#define WS_G       (WS_TOK + 12800)           // 64*200*200*8 = 20480000
// total ~25.3 MB

// ---------------------------------------------------------------------------
// Kernel A: masked-mean frame_repr (fp64), LayerNorm -> h32, L2-normalized
// fn64, valid flags. One block per (b,t); threads 0..191 own 4 dims (float4).
// ---------------------------------------------------------------------------
__global__ __launch_bounds__(256) void kA(const float* __restrict__ x,
                                          const float* __restrict__ mask,
                                          const float* __restrict__ gamma,
                                          const float* __restrict__ beta,
                                          double* __restrict__ fn64,
                                          float* __restrict__ h32,
                                          int* __restrict__ validw) {
  const int row = blockIdx.x;          // b*T + t
  const int tid = threadIdx.x;
  __shared__ float  ms[N_];
  __shared__ double red[256];
  __shared__ double sh_denom, sh_mu, sh_sd, sh_nrm;
  const float* xr = x + (size_t)row * (N_ * D_);

  if (tid < N_) ms[tid] = mask[(size_t)row * N_ + tid];
  __syncthreads();

  // denom = clip(sum(mask), 1e-6)
  red[tid] = (tid < N_) ? (double)ms[tid] : 0.0;
  __syncthreads();
  for (int s = 128; s > 0; s >>= 1) { if (tid < s) red[tid] += red[tid + s]; __syncthreads(); }
  if (tid == 0) { double d = red[0]; sh_denom = (d > 1e-6) ? d : 1e-6; }
  __syncthreads();
  const double dn = sh_denom;

  // masked mean over n (fp64 accumulate), float4 vector loads
  double a0 = 0.0, a1 = 0.0, a2 = 0.0, a3 = 0.0;
  if (tid < 192) {
    const float* px = xr + tid * 4;
#pragma unroll 4
    for (int n = 0; n < N_; n++) {
      const double mv = (double)ms[n];
      const float4 v = *(const float4*)(px + (size_t)n * D_);
      a0 += (double)v.x * mv;
      a1 += (double)v.y * mv;
      a2 += (double)v.z * mv;
      a3 += (double)v.w * mv;
    }
  }
  const double f0 = a0 / dn, f1 = a1 / dn, f2 = a2 / dn, f3 = a3 / dn;

  // mean
  red[tid] = (tid < 192) ? (f0 + f1 + f2 + f3) : 0.0; __syncthreads();
  for (int s = 128; s > 0; s >>= 1) { if (tid < s) red[tid] += red[tid + s]; __syncthreads(); }
  if (tid == 0) sh_mu = red[0] / (double)D_;
  __syncthreads();
  const double mu = sh_mu;

  // L2 norm (cosine normalize, eps 1e-12)
  red[tid] = (tid < 192) ? (f0 * f0 + f1 * f1 + f2 * f2 + f3 * f3) : 0.0; __syncthreads();
  for (int s = 128; s > 0; s >>= 1) { if (tid < s) red[tid] += red[tid + s]; __syncthreads(); }
  if (tid == 0) { double nr = sqrt(red[0]); sh_nrm = (nr > 1e-12) ? nr : 1e-12; }
  __syncthreads();

  // variance
  red[tid] = (tid < 192) ? ((f0 - mu) * (f0 - mu) + (f1 - mu) * (f1 - mu) +
                            (f2 - mu) * (f2 - mu) + (f3 - mu) * (f3 - mu)) : 0.0;
  __syncthreads();
  for (int s = 128; s > 0; s >>= 1) { if (tid < s) red[tid] += red[tid + s]; __syncthreads(); }
  if (tid == 0) sh_sd = sqrt(red[0] / (double)D_ + 1e-5);
  __syncthreads();
  const double sd = sh_sd, nrm = sh_nrm;

  if (tid < 192) {
    const size_t base = (size_t)row * D_;
    const float4 g  = ((const float4*)gamma)[tid];
    const float4 be = ((const float4*)beta)[tid];
    float4 hv;
    hv.x = (float)((f0 - mu) / sd * (double)g.x + (double)be.x);
    hv.y = (float)((f1 - mu) / sd * (double)g.y + (double)be.y);
    hv.z = (float)((f2 - mu) / sd * (double)g.z + (double)be.z);
    hv.w = (float)((f3 - mu) / sd * (double)g.w + (double)be.w);
    *(float4*)(h32 + base + tid * 4) = hv;
    double2* fp = (double2*)(fn64 + base + tid * 4);
    fp[0] = make_double2(f0 / nrm, f1 / nrm);
    fp[1] = make_double2(f2 / nrm, f3 / nrm);
  }
  if (tid == 0) validw[row] = 1;  // clip(denom,1e-6) > 0 always
}

// ---------------------------------------------------------------------------
// Kernel B: score partials = gelu(h @ W1 + b1) @ W2 per n-block.
// Tiled fp32 GEMM M=512 N=3072 K=768; Mtile=32, Ntile=128, BK=64.
// fp64 GELU/W2 epilogue; partial per (row, nblock) -> ws (no atomics).
// ---------------------------------------------------------------------------
__global__ __launch_bounds__(256) void kB(const float* __restrict__ h32,
                                          const float* __restrict__ W1,
                                          const float* __restrict__ b1,
                                          const float* __restrict__ W2,
                                          double* __restrict__ scorep) {
  const int n0 = blockIdx.x * 128;
  const int m0 = blockIdx.y * 32;
  const int tid = threadIdx.x;
  const int tx = tid & 31;   // 32 col-groups of 4
  const int ty = tid >> 5;   // 8 row-groups of 4
  __shared__ float As[64 * 33];   // [k][m], padded
  __shared__ float Bs[64 * 128];  // [k][n]
  float acc[4][4];
#pragma unroll
  for (int r = 0; r < 4; r++)
#pragma unroll
    for (int c = 0; c < 4; c++) acc[r][c] = 0.0f;

  for (int kc = 0; kc < 12; kc++) {
    const int k0 = kc * 64;
#pragma unroll
    for (int it = 0; it < 8; it++) {           // A: 32x64
      int idx = tid + (it << 8);
      int k = idx & 63, m = idx >> 6;
      As[k * 33 + m] = h32[(size_t)(m0 + m) * D_ + k0 + k];
    }
#pragma unroll
    for (int it = 0; it < 8; it++) {           // B: 64x128 float4
      int idx = tid + (it << 8);
      int k = idx >> 5, n4 = idx & 31;
      const float4 v = *(const float4*)(W1 + (size_t)(k0 + k) * HIDD_ + n0 + (n4 << 2));
      *(float4*)(Bs + k * 128 + (n4 << 2)) = v;
    }
    __syncthreads();
#pragma unroll 16
    for (int kk = 0; kk < 64; kk++) {
      float a[4], bb[4];
#pragma unroll
      for (int r = 0; r < 4; r++) a[r] = As[kk * 33 + ty * 4 + r];
#pragma unroll
      for (int c = 0; c < 4; c++) bb[c] = Bs[kk * 128 + tx * 4 + c];
#pragma unroll
      for (int r = 0; r < 4; r++)
#pragma unroll
        for (int c = 0; c < 4; c++) acc[r][c] += a[r] * bb[c];
    }
    __syncthreads();
  }

  double part[4] = {0.0, 0.0, 0.0, 0.0};
#pragma unroll
  for (int r = 0; r < 4; r++) {
#pragma unroll
    for (int c = 0; c < 4; c++) {
      const int gn = n0 + tx * 4 + c;
      const double v = (double)(acc[r][c] + b1[gn]);
      const double g = 0.5 * v * (1.0 + erf(v * 0.7071067811865475244));
      part[r] += g * (double)W2[gn];
    }
  }
#pragma unroll
  for (int r = 0; r < 4; r++) {
    double s = part[r];
#pragma unroll
    for (int off = 16; off > 0; off >>= 1) s += __shfl_down(s, off, 32);
    if (tx == 0) scorep[(size_t)(m0 + ty * 4 + r) * 24 + blockIdx.x] = s;
  }
}

// ---------------------------------------------------------------------------
// Kernel D: facility-location greedy frame selection. One block per batch,
// 256 threads. sim = fn.fn^T (fp64) via 4x4 register micro-tiles.
// Sums kB's 24 score partials per row (fixed order).
// ---------------------------------------------------------------------------
__global__ __launch_bounds__(256) void kD(const double* __restrict__ fn64,
                                          const double* __restrict__ scorep,
                                          const int* __restrict__ validw,
                                          const float* __restrict__ b2,
                                          int* __restrict__ fidxw,
                                          float* __restrict__ out_fidx,
                                          float* __restrict__ out_fmask) {
  const int b = blockIdx.x;
  const int tid = threadIdx.x;
  __shared__ double fnS[64 * 65];
  __shared__ double sim[64 * 64];
  __shared__ double scoreS[64];
  __shared__ double bc[64];
  __shared__ int chosenS[64];
  __shared__ int validS[64];

  const int i0 = (tid >> 4) << 2;
  const int j0 = (tid & 15) << 2;
  double acc[4][4];
#pragma unroll
  for (int r = 0; r < 4; r++)
#pragma unroll
    for (int c = 0; c < 4; c++) acc[r][c] = 0.0;

  for (int c = 0; c < 12; c++) {
#pragma unroll
    for (int it = 0; it < 16; it++) {
      int idx = (it << 8) + tid;
      int t = idx >> 6, kk = idx & 63;
      fnS[t * 65 + kk] = fn64[((size_t)(b * T_ + t)) * D_ + c * 64 + kk];
    }
    __syncthreads();
#pragma unroll 4
    for (int kk = 0; kk < 64; kk++) {
      double a[4], bb[4];
#pragma unroll
      for (int r = 0; r < 4; r++) a[r] = fnS[(i0 + r) * 65 + kk];
#pragma unroll
      for (int cc = 0; cc < 4; cc++) bb[cc] = fnS[(j0 + cc) * 65 + kk];
#pragma unroll
      for (int r = 0; r < 4; r++)
#pragma unroll
        for (int cc = 0; cc < 4; cc++) acc[r][cc] += a[r] * bb[cc];
    }
    __syncthreads();
  }
#pragma unroll
  for (int r = 0; r < 4; r++)
#pragma unroll
    for (int cc = 0; cc < 4; cc++) sim[(i0 + r) * 64 + (j0 + cc)] = acc[r][cc];

  if (tid < 64) {
    double s = 0.0;
    const double* sp = scorep + (size_t)(b * T_ + tid) * 24;
    for (int q = 0; q < 24; q++) s += sp[q];
    scoreS[tid]  = s + (double)b2[0];
    validS[tid]  = validw[b * T_ + tid];
    bc[tid]      = 0.0;
    chosenS[tid] = 0;
  }
  __syncthreads();

  for (int step = 0; step < KF_; step++) {
    if (tid < 64) {
      double g = 0.0;
      for (int ii = 0; ii < 64; ii++) g += fmax(bc[ii], sim[ii * 64 + tid]);
      double bs = bc[tid];
#pragma unroll
      for (int off = 32; off > 0; off >>= 1) bs += __shfl_down(bs, off, 64);
      bs = __shfl(bs, 0, 64);
      double tot = g - bs + 0.5 * scoreS[tid];
      if (!validS[tid] || chosenS[tid]) tot = -INFINITY;
      double bv = tot; int bi = tid;
#pragma unroll
      for (int off = 32; off > 0; off >>= 1) {
        double ov = __shfl_down(bv, off, 64);
        int    oi = __shfl_down(bi, off, 64);
        if (ov > bv || (ov == bv && oi < bi)) { bv = ov; bi = oi; }
      }
      bi = __shfl(bi, 0, 64);
      bc[tid] = fmax(bc[tid], sim[tid * 64 + bi]);
      if (tid == bi) chosenS[tid] = 1;
      if (tid == 0) {
        fidxw[b * KF_ + step] = bi;
        out_fidx[b * KF_ + step] = (float)bi;
      }
    }
    __syncthreads();
  }
  if (tid < 64) out_fmask[b * T_ + tid] = chosenS[tid] ? 1.0f : 0.0f;
}

// ---------------------------------------------------------------------------
// Kernel G: per-pair Gram matrix G[i][j] = dot(X_i, X_j) in fp64.
// Grid = 64 pairs x 10 symmetric 64x64 tiles. 256 threads, 4x4 strided
// micro-tiles, K-chunks of 32 staged in LDS as fp64 ([kk][row], pad 65).
// ---------------------------------------------------------------------------
__global__ __launch_bounds__(256) void kG(const float* __restrict__ x,
                                          const int* __restrict__ fidxw,
                                          double* __restrict__ G) {
  static const int TIa[10] = {0,0,0,0,1,1,1,2,2,3};
  static const int TJa[10] = {0,1,2,3,1,2,3,2,3,3};
  const int p  = blockIdx.x / 10;
  const int t  = blockIdx.x - p * 10;
  const int ti = TIa[t], tj = TJa[t];
  const int b  = p >> 3;
  const int fi = fidxw[p];
  const float* X = x + ((size_t)(b * T_ + fi)) * (N_ * D_);
  double* Gp = G + (size_t)p * (GSTRIDE * GSTRIDE);

  __shared__ double As[32 * 65];
  __shared__ double Bs[32 * 65];
  const int tid = threadIdx.x;
  const int tx = tid & 15;        // col group
  const int ty = tid >> 4;        // row group (0..15)
  double acc[4][4];
#pragma unroll
  for (int r = 0; r < 4; r++)
#pragma unroll
    for (int c = 0; c < 4; c++) acc[r][c] = 0.0;

  for (int kc = 0; kc < 24; kc++) {
#pragma unroll
    for (int it = 0; it < 2; it++) {
      const int idx = (it << 8) + tid;      // 0..511
      const int row = idx >> 3;             // 0..63
      const int kg  = idx & 7;              // float4 group within 32-k chunk
      const int gra = ti * 64 + row, grb = tj * 64 + row;
      const int ra = (gra < N_) ? gra : (N_ - 1);
      const int rb = (grb < N_) ? grb : (N_ - 1);
      const float4 va = *(const float4*)(X + (size_t)ra * D_ + kc * 32 + kg * 4);
      const float4 vb = *(const float4*)(X + (size_t)rb * D_ + kc * 32 + kg * 4);
      As[(kg * 4 + 0) * 65 + row] = (double)va.x;
      As[(kg * 4 + 1) * 65 + row] = (double)va.y;
      As[(kg * 4 + 2) * 65 + row] = (double)va.z;
      As[(kg * 4 + 3) * 65 + row] = (double)va.w;
      Bs[(kg * 4 + 0) * 65 + row] = (double)vb.x;
      Bs[(kg * 4 + 1) * 65 + row] = (double)vb.y;
      Bs[(kg * 4 + 2) * 65 + row] = (double)vb.z;
      Bs[(kg * 4 + 3) * 65 + row] = (double)vb.w;
    }
    __syncthreads();
#pragma unroll 8
    for (int kk = 0; kk < 32; kk++) {
      double a[4], bb[4];
#pragma unroll
      for (int q = 0; q < 4; q++) a[q]  = As[kk * 65 + ty + 16 * q];
#pragma unroll
      for (int q = 0; q < 4; q++) bb[q] = Bs[kk * 65 + tx + 16 * q];
#pragma unroll
      for (int r = 0; r < 4; r++)
#pragma unroll
        for (int c = 0; c < 4; c++) acc[r][c] += a[r] * bb[c];
    }
    __syncthreads();
  }

#pragma unroll
  for (int r = 0; r < 4; r++) {
    const int gi = ti * 64 + ty + 16 * r;
#pragma unroll
    for (int c = 0; c < 4; c++) {
      const int gj = tj * 64 + tx + 16 * c;
      if (gi < N_ && gj < N_) {
        Gp[(size_t)gi * GSTRIDE + gj] = acc[r][c];
        if (ti != tj) Gp[(size_t)gj * GSTRIDE + gi] = acc[r][c];
      }
    }
  }
}

// ---------------------------------------------------------------------------
// Kernel E2: sequential FPS using precomputed Gram. One block per pair,
// 256 threads; thread n owns md[n] in a register. Per step: read G row of
// cand (1576 B, L2-hot), dist = sqrt(max(Gnn - 2Gnc + Gcc, 0)), argmax.
// ---------------------------------------------------------------------------
__global__ __launch_bounds__(256) void kE2(const double* __restrict__ G,
                                           const float* __restrict__ mask,
                                           const int* __restrict__ fidxw,
                                           int* __restrict__ tokw) {
  const int p = blockIdx.x;
  const int b = p >> 3;
  const int fi = fidxw[p];
  const double* Gp = G + (size_t)p * (GSTRIDE * GSTRIDE);
  const float* mrow = mask + (size_t)(b * T_ + fi) * N_;
  const int tid = threadIdx.x;
  const bool live = tid < N_;

  __shared__ double gds[N_];
  __shared__ double bvS[4];
  __shared__ int biS[4];
  __shared__ int candS;

  const int valid = (live && mrow[tid] > 0.5f) ? 1 : 0;
  const double gd = live ? Gp[(size_t)tid * GSTRIDE + tid] : 0.0;
  if (live) gds[tid] = gd;
  __syncthreads();

  // per-thread value -> block argmax (first-index tie-break); returns idx
  auto argmax = [&](double v) -> int {
    double bv = v; int bi = tid;
#pragma unroll
    for (int off = 32; off > 0; off >>= 1) {
      const double ov = __shfl_down(bv, off, 64);
      const int    oi = __shfl_down(bi, off, 64);
      if (ov > bv || (ov == bv && oi < bi)) { bv = ov; bi = oi; }
    }
    const int w = tid >> 6;
    if ((tid & 63) == 0) { bvS[w] = bv; biS[w] = bi; }
    __syncthreads();
    if (tid == 0) {
      double B0 = bvS[0]; int best = biS[0];
      for (int q = 1; q < 4; q++)
        if (bvS[q] > B0) { B0 = bvS[q]; best = biS[q]; }  // waves ordered by idx
      candS = best;
    }
    __syncthreads();
    return candS;
  };

  // first = argmax(valid ? ||X_n||^2 : -inf)
  int cand = argmax((live && valid) ? gd : -INFINITY);
  if (tid == 0) tokw[p * KT_] = cand;

  double md = -INFINITY;
  for (int k = 1; k < KT_; k++) {
    const double gdc = gds[cand];
    const double g = live ? Gp[(size_t)cand * GSTRIDE + tid] : 0.0;
    const double dist = sqrt(fmax(gd + gdc - 2.0 * g, 0.0));
    if (live) md = valid ? ((k == 1) ? dist : fmin(md, dist)) : -1.0;
    cand = argmax(md);
    if (tid == 0) tokw[p * KT_ + k] = cand;
  }
}

// ---------------------------------------------------------------------------
// Kernel F: gather z rows, write token_idx (as float), scatter token_mask.
// Wave-per-row, float4 copies. 4 rows per 256-thread block.
// ---------------------------------------------------------------------------
__global__ __launch_bounds__(256) void kF(const float* __restrict__ x,
                                          const int* __restrict__ fidxw,
                                          const int* __restrict__ tokw,
                                          float* __restrict__ out) {
  const int row = blockIdx.x * 4 + (threadIdx.x >> 6);  // pair*KT + kt
  const int lane = threadIdx.x & 63;
  const int pair = row / KT_;
  const int b = pair >> 3;
  const int fi = fidxw[pair];
  const int tok = tokw[row];
  const float* src = x + (((size_t)(b * T_ + fi)) * N_ + tok) * D_;
  float* dst = out + (size_t)row * D_;
#pragma unroll
  for (int r = 0; r < 3; r++) {
    const int d = lane * 4 + 256 * r;
    *(float4*)(dst + d) = *(const float4*)(src + d);
  }
  if (lane == 0) {
    out[TI_OFF + row] = (float)tok;
    out[TM_OFF + (size_t)(b * T_ + fi) * N_ + tok] = 1.0f;
  }
}

// ---------------------------------------------------------------------------
extern "C" void kernel_launch(void* const* d_in, const int* in_sizes, int n_in,
                              void* d_out, int out_size, void* d_ws, size_t ws_size,
                              hipStream_t stream) {
  (void)in_sizes; (void)n_in; (void)ws_size; (void)out_size;
  const float* x     = (const float*)d_in[0];
  const float* mask  = (const float*)d_in[1];
  const float* gamma = (const float*)d_in[2];
  const float* beta  = (const float*)d_in[3];
  const float* W1    = (const float*)d_in[4];
  const float* b1    = (const float*)d_in[5];
  const float* W2    = (const float*)d_in[6];
  const float* b2    = (const float*)d_in[7];
  float* out = (float*)d_out;
  char* ws = (char*)d_ws;

  double* scorep = (double*)(ws + WS_SCOREP);
  double* fn64   = (double*)(ws + WS_FN64);
  float*  h32    = (float*)(ws + WS_H32);
  int*    validw = (int*)(ws + WS_VALID);
  int*    fidxw  = (int*)(ws + WS_FIDX);
  int*    tokw   = (int*)(ws + WS_TOK);
  double* G      = (double*)(ws + WS_G);

  // zero only the token_mask region (everything else is fully overwritten)
  hipMemsetAsync(out + TM_OFF, 0, (size_t)TM_SZ * sizeof(float), stream);

  kA<<<B_ * T_, 256, 0, stream>>>(x, mask, gamma, beta, fn64, h32, validw);
  kB<<<dim3(HIDD_ / 128, (B_ * T_) / 32), 256, 0, stream>>>(h32, W1, b1, W2, scorep);
  kD<<<B_, 256, 0, stream>>>(fn64, scorep, validw, b2, fidxw, out + FI_OFF, out + FM_OFF);
  kG<<<B_ * KF_ * 10, 256, 0, stream>>>(x, fidxw, G);
  kE2<<<B_ * KF_, 256, 0, stream>>>(G, mask, fidxw, tokw);
  kF<<<B_ * KF_ * KT_ / 4, 256, 0, stream>>>(x, fidxw, tokw, out);
}

// Round 4
// 764.299 us; speedup vs baseline: 3.3842x; 1.0903x over previous
//
#include <hip/hip_runtime.h>
#include <math.h>

// Problem constants
#define B_ 8
#define T_ 64
#define N_ 197
#define D_ 768
#define HIDD_ 3072   // HID*D
#define KF_ 8
#define KT_ 49
#define GSTRIDE 200  // padded row stride of per-pair Gram matrix (doubles)

// Output layout (floats, concatenated in reference return order)
#define Z_SZ    (B_*KF_*KT_*D_)       // 2408448
#define FI_OFF  (Z_SZ)                // 2408448
#define TI_OFF  (FI_OFF + B_*KF_)     // 2408512
#define FM_OFF  (TI_OFF + B_*KF_*KT_) // 2411648
#define TM_OFF  (FM_OFF + B_*T_)      // 2412160
#define TM_SZ   (B_*T_*N_)            // 100864

// Workspace layout (bytes)
#define WS_SCOREP  0                          // 512*24 doubles = 98304
#define WS_FN64    98304                      // 512*768*8 = 3145728
#define WS_H32     (WS_FN64 + 3145728)        // 512*768*4 = 1572864
#define WS_VALID   (WS_H32 + 1572864)         // 512*4 = 2048
#define WS_FIDX    (WS_VALID + 2048)          // 64 ints (pad 256)
#define WS_SIM     (WS_FIDX + 256)            // 8*64*64*8 = 262144
#define WS_G       (WS_SIM + 262144)          // 64*200*200*8 = 20480000
// total ~25.6 MB

// ---------------------------------------------------------------------------
// Kernel A: masked-mean frame_repr (fp64), LayerNorm -> h32, L2-normalized
// fn64, valid flags. One block per (b,t); threads 0..191 own 4 dims (float4).
// ---------------------------------------------------------------------------
__global__ __launch_bounds__(256) void kA(const float* __restrict__ x,
                                          const float* __restrict__ mask,
                                          const float* __restrict__ gamma,
                                          const float* __restrict__ beta,
                                          double* __restrict__ fn64,
                                          float* __restrict__ h32,
                                          int* __restrict__ validw) {
  const int row = blockIdx.x;          // b*T + t
  const int tid = threadIdx.x;
  __shared__ float  ms[N_];
  __shared__ double red[256];
  __shared__ double sh_denom, sh_mu, sh_sd, sh_nrm;
  const float* xr = x + (size_t)row * (N_ * D_);

  if (tid < N_) ms[tid] = mask[(size_t)row * N_ + tid];
  __syncthreads();

  // denom = clip(sum(mask), 1e-6)
  red[tid] = (tid < N_) ? (double)ms[tid] : 0.0;
  __syncthreads();
  for (int s = 128; s > 0; s >>= 1) { if (tid < s) red[tid] += red[tid + s]; __syncthreads(); }
  if (tid == 0) { double d = red[0]; sh_denom = (d > 1e-6) ? d : 1e-6; }
  __syncthreads();
  const double dn = sh_denom;

  // masked mean over n (fp64 accumulate), float4 vector loads
  double a0 = 0.0, a1 = 0.0, a2 = 0.0, a3 = 0.0;
  if (tid < 192) {
    const float* px = xr + tid * 4;
#pragma unroll 4
    for (int n = 0; n < N_; n++) {
      const double mv = (double)ms[n];
      const float4 v = *(const float4*)(px + (size_t)n * D_);
      a0 += (double)v.x * mv;
      a1 += (double)v.y * mv;
      a2 += (double)v.z * mv;
      a3 += (double)v.w * mv;
    }
  }
  const double f0 = a0 / dn, f1 = a1 / dn, f2 = a2 / dn, f3 = a3 / dn;

  // mean
  red[tid] = (tid < 192) ? (f0 + f1 + f2 + f3) : 0.0; __syncthreads();
  for (int s = 128; s > 0; s >>= 1) { if (tid < s) red[tid] += red[tid + s]; __syncthreads(); }
  if (tid == 0) sh_mu = red[0] / (double)D_;
  __syncthreads();
  const double mu = sh_mu;

  // L2 norm (cosine normalize, eps 1e-12)
  red[tid] = (tid < 192) ? (f0 * f0 + f1 * f1 + f2 * f2 + f3 * f3) : 0.0; __syncthreads();
  for (int s = 128; s > 0; s >>= 1) { if (tid < s) red[tid] += red[tid + s]; __syncthreads(); }
  if (tid == 0) { double nr = sqrt(red[0]); sh_nrm = (nr > 1e-12) ? nr : 1e-12; }
  __syncthreads();

  // variance
  red[tid] = (tid < 192) ? ((f0 - mu) * (f0 - mu) + (f1 - mu) * (f1 - mu) +
                            (f2 - mu) * (f2 - mu) + (f3 - mu) * (f3 - mu)) : 0.0;
  __syncthreads();
  for (int s = 128; s > 0; s >>= 1) { if (tid < s) red[tid] += red[tid + s]; __syncthreads(); }
  if (tid == 0) sh_sd = sqrt(red[0] / (double)D_ + 1e-5);
  __syncthreads();
  const double sd = sh_sd, nrm = sh_nrm;

  if (tid < 192) {
    const size_t base = (size_t)row * D_;
    const float4 g  = ((const float4*)gamma)[tid];
    const float4 be = ((const float4*)beta)[tid];
    float4 hv;
    hv.x = (float)((f0 - mu) / sd * (double)g.x + (double)be.x);
    hv.y = (float)((f1 - mu) / sd * (double)g.y + (double)be.y);
    hv.z = (float)((f2 - mu) / sd * (double)g.z + (double)be.z);
    hv.w = (float)((f3 - mu) / sd * (double)g.w + (double)be.w);
    *(float4*)(h32 + base + tid * 4) = hv;
    double2* fp = (double2*)(fn64 + base + tid * 4);
    fp[0] = make_double2(f0 / nrm, f1 / nrm);
    fp[1] = make_double2(f2 / nrm, f3 / nrm);
  }
  if (tid == 0) validw[row] = 1;  // clip(denom,1e-6) > 0 always
}

// ---------------------------------------------------------------------------
// Kernel B: score partials = gelu(h @ W1 + b1) @ W2 per n-block.
// Tiled fp32 GEMM M=512 N=3072 K=768; Mtile=32, Ntile=128, BK=64.
// As pad = 36 (mult of 4) so the a[4]/b[4] micro-tile reads are 16B-aligned
// ds_read_b128 (was pad 33 -> scalar b32 reads, LDS-bound).
// fp64 GELU/W2 epilogue; partial per (row, nblock) -> ws (no atomics).
// ---------------------------------------------------------------------------
__global__ __launch_bounds__(256) void kB(const float* __restrict__ h32,
                                          const float* __restrict__ W1,
                                          const float* __restrict__ b1,
                                          const float* __restrict__ W2,
                                          double* __restrict__ scorep) {
  const int n0 = blockIdx.x * 128;
  const int m0 = blockIdx.y * 32;
  const int tid = threadIdx.x;
  const int tx = tid & 31;   // 32 col-groups of 4
  const int ty = tid >> 5;   // 8 row-groups of 4
  __shared__ float As[64 * 36];   // [k][m], pad 36 -> b128-aligned
  __shared__ float Bs[64 * 128];  // [k][n]
  float acc[4][4];
#pragma unroll
  for (int r = 0; r < 4; r++)
#pragma unroll
    for (int c = 0; c < 4; c++) acc[r][c] = 0.0f;

  for (int kc = 0; kc < 12; kc++) {
    const int k0 = kc * 64;
#pragma unroll
    for (int it = 0; it < 8; it++) {           // A: 32x64
      int idx = tid + (it << 8);
      int k = idx & 63, m = idx >> 6;
      As[k * 36 + m] = h32[(size_t)(m0 + m) * D_ + k0 + k];
    }
#pragma unroll
    for (int it = 0; it < 8; it++) {           // B: 64x128 float4
      int idx = tid + (it << 8);
      int k = idx >> 5, n4 = idx & 31;
      const float4 v = *(const float4*)(W1 + (size_t)(k0 + k) * HIDD_ + n0 + (n4 << 2));
      *(float4*)(Bs + k * 128 + (n4 << 2)) = v;
    }
    __syncthreads();
#pragma unroll 16
    for (int kk = 0; kk < 64; kk++) {
      float4 av = *(const float4*)(As + kk * 36 + ty * 4);
      float4 bv = *(const float4*)(Bs + kk * 128 + tx * 4);
      const float a[4] = {av.x, av.y, av.z, av.w};
      const float bb[4] = {bv.x, bv.y, bv.z, bv.w};
#pragma unroll
      for (int r = 0; r < 4; r++)
#pragma unroll
        for (int c = 0; c < 4; c++) acc[r][c] += a[r] * bb[c];
    }
    __syncthreads();
  }

  double part[4] = {0.0, 0.0, 0.0, 0.0};
#pragma unroll
  for (int r = 0; r < 4; r++) {
#pragma unroll
    for (int c = 0; c < 4; c++) {
      const int gn = n0 + tx * 4 + c;
      const double v = (double)(acc[r][c] + b1[gn]);
      const double g = 0.5 * v * (1.0 + erf(v * 0.7071067811865475244));
      part[r] += g * (double)W2[gn];
    }
  }
#pragma unroll
  for (int r = 0; r < 4; r++) {
    double s = part[r];
#pragma unroll
    for (int off = 16; off > 0; off >>= 1) s += __shfl_down(s, off, 32);
    if (tx == 0) scorep[(size_t)(m0 + ty * 4 + r) * 24 + blockIdx.x] = s;
  }
}

// ---------------------------------------------------------------------------
// Kernel S: parallel sim = fn.fn^T (fp64). Grid = 8 batches x 4 row-slabs
// of 16. 256 threads: ty=row (16), tx=col-group (16 x4). Same k-summation
// order as the old fused version -> bit-identical sim values.
// ---------------------------------------------------------------------------
__global__ __launch_bounds__(256) void kS(const double* __restrict__ fn64,
                                          double* __restrict__ simG) {
  const int b    = blockIdx.x >> 2;
  const int tile = blockIdx.x & 3;
  const int tid = threadIdx.x;
  const int ty = tid >> 4;          // row within slab (0..15)
  const int tx = tid & 15;          // col group (0..15)
  __shared__ double As[64 * 17];    // [kk][row16+pad]
  __shared__ double Bs[64 * 66];    // [kk][col64+pad2]
  double acc[4] = {0.0, 0.0, 0.0, 0.0};

  for (int kc = 0; kc < 12; kc++) {
#pragma unroll
    for (int it = 0; it < 4; it++) {          // A slab: 16x64 dbl
      const int idx = (it << 8) + tid;
      const int row = idx >> 6, kk = idx & 63;
      As[kk * 17 + row] = fn64[((size_t)(b * T_ + tile * 16 + row)) * D_ + kc * 64 + kk];
    }
#pragma unroll
    for (int it = 0; it < 16; it++) {         // B slab: 64x64 dbl
      const int idx = (it << 8) + tid;
      const int row = idx >> 6, kk = idx & 63;
      Bs[kk * 66 + row] = fn64[((size_t)(b * T_ + row)) * D_ + kc * 64 + kk];
    }
    __syncthreads();
#pragma unroll 8
    for (int kk = 0; kk < 64; kk++) {
      const double a = As[kk * 17 + ty];
      const double* bp = Bs + kk * 66 + tx * 4;
      acc[0] += a * bp[0];
      acc[1] += a * bp[1];
      acc[2] += a * bp[2];
      acc[3] += a * bp[3];
    }
    __syncthreads();
  }
  double* o = simG + ((size_t)b * 64 + tile * 16 + ty) * 64 + tx * 4;
  o[0] = acc[0]; o[1] = acc[1]; o[2] = acc[2]; o[3] = acc[3];
}

// ---------------------------------------------------------------------------
// Kernel D: facility-location greedy (reads precomputed sim). One block per
// batch; 256 threads load sim into LDS, wave 0 runs the 8 greedy steps.
// ---------------------------------------------------------------------------
__global__ __launch_bounds__(256) void kD(const double* __restrict__ simG,
                                          const double* __restrict__ scorep,
                                          const int* __restrict__ validw,
                                          const float* __restrict__ b2,
                                          int* __restrict__ fidxw,
                                          float* __restrict__ out_fidx,
                                          float* __restrict__ out_fmask) {
  const int b = blockIdx.x;
  const int tid = threadIdx.x;
  __shared__ double sim[64 * 64];
  __shared__ double scoreS[64];
  __shared__ double bc[64];
  __shared__ int chosenS[64];
  __shared__ int validS[64];

  const double2* sp = (const double2*)(simG + (size_t)b * 4096);
#pragma unroll
  for (int it = 0; it < 8; it++) {
    const int idx = (it << 8) + tid;
    ((double2*)sim)[idx] = sp[idx];
  }
  if (tid < 64) {
    double s = 0.0;
    const double* pp = scorep + (size_t)(b * T_ + tid) * 24;
    for (int q = 0; q < 24; q++) s += pp[q];
    scoreS[tid]  = s + (double)b2[0];
    validS[tid]  = validw[b * T_ + tid];
    bc[tid]      = 0.0;
    chosenS[tid] = 0;
  }
  __syncthreads();

  for (int step = 0; step < KF_; step++) {
    if (tid < 64) {
      double g = 0.0;
      for (int ii = 0; ii < 64; ii++) g += fmax(bc[ii], sim[ii * 64 + tid]);
      double bs = bc[tid];
#pragma unroll
      for (int off = 32; off > 0; off >>= 1) bs += __shfl_down(bs, off, 64);
      bs = __shfl(bs, 0, 64);
      double tot = g - bs + 0.5 * scoreS[tid];
      if (!validS[tid] || chosenS[tid]) tot = -INFINITY;
      double bv = tot; int bi = tid;
#pragma unroll
      for (int off = 32; off > 0; off >>= 1) {
        double ov = __shfl_down(bv, off, 64);
        int    oi = __shfl_down(bi, off, 64);
        if (ov > bv || (ov == bv && oi < bi)) { bv = ov; bi = oi; }
      }
      bi = __shfl(bi, 0, 64);
      bc[tid] = fmax(bc[tid], sim[tid * 64 + bi]);
      if (tid == bi) chosenS[tid] = 1;
      if (tid == 0) {
        fidxw[b * KF_ + step] = bi;
        out_fidx[b * KF_ + step] = (float)bi;
      }
    }
    __syncthreads();
  }
  if (tid < 64) out_fmask[b * T_ + tid] = chosenS[tid] ? 1.0f : 0.0f;
}

// ---------------------------------------------------------------------------
// Kernel G: per-pair Gram matrix G[i][j] = dot(X_i, X_j), fp64 accumulate.
// LDS stages fp32 (exact input values; cvt->fp64 in regs => bit-identical
// to fp64 staging, half the LDS traffic). Pad 68 -> b128-aligned reads.
// Grid = 64 pairs x 10 symmetric 64x64 tiles; 4x4 consecutive micro-tiles.
// ---------------------------------------------------------------------------
__global__ __launch_bounds__(256) void kG(const float* __restrict__ x,
                                          const int* __restrict__ fidxw,
                                          double* __restrict__ G) {
  static const int TIa[10] = {0,0,0,0,1,1,1,2,2,3};
  static const int TJa[10] = {0,1,2,3,1,2,3,2,3,3};
  const int p  = blockIdx.x / 10;
  const int t  = blockIdx.x - p * 10;
  const int ti = TIa[t], tj = TJa[t];
  const int b  = p >> 3;
  const int fi = fidxw[p];
  const float* X = x + ((size_t)(b * T_ + fi)) * (N_ * D_);
  double* Gp = G + (size_t)p * (GSTRIDE * GSTRIDE);

  __shared__ float As[32 * 68];   // [kk][row64+pad4]
  __shared__ float Bs[32 * 68];
  const int tid = threadIdx.x;
  const int tx = tid & 15;        // col group (x4, consecutive)
  const int ty = tid >> 4;        // row group (x4, consecutive)
  double acc[4][4];
#pragma unroll
  for (int r = 0; r < 4; r++)
#pragma unroll
    for (int c = 0; c < 4; c++) acc[r][c] = 0.0;

  for (int kc = 0; kc < 24; kc++) {
#pragma unroll
    for (int it = 0; it < 2; it++) {
      const int idx = (it << 8) + tid;      // 0..511
      const int row = idx >> 3;             // 0..63
      const int kg  = idx & 7;              // float4 group within 32-k chunk
      const int gra = ti * 64 + row, grb = tj * 64 + row;
      const int ra = (gra < N_) ? gra : (N_ - 1);
      const int rb = (grb < N_) ? grb : (N_ - 1);
      const float4 va = *(const float4*)(X + (size_t)ra * D_ + kc * 32 + kg * 4);
      const float4 vb = *(const float4*)(X + (size_t)rb * D_ + kc * 32 + kg * 4);
      As[(kg * 4 + 0) * 68 + row] = va.x;
      As[(kg * 4 + 1) * 68 + row] = va.y;
      As[(kg * 4 + 2) * 68 + row] = va.z;
      As[(kg * 4 + 3) * 68 + row] = va.w;
      Bs[(kg * 4 + 0) * 68 + row] = vb.x;
      Bs[(kg * 4 + 1) * 68 + row] = vb.y;
      Bs[(kg * 4 + 2) * 68 + row] = vb.z;
      Bs[(kg * 4 + 3) * 68 + row] = vb.w;
    }
    __syncthreads();
#pragma unroll 8
    for (int kk = 0; kk < 32; kk++) {
      const float4 av = *(const float4*)(As + kk * 68 + ty * 4);
      const float4 bv = *(const float4*)(Bs + kk * 68 + tx * 4);
      const double a[4]  = {(double)av.x, (double)av.y, (double)av.z, (double)av.w};
      const double bb[4] = {(double)bv.x, (double)bv.y, (double)bv.z, (double)bv.w};
#pragma unroll
      for (int r = 0; r < 4; r++)
#pragma unroll
        for (int c = 0; c < 4; c++) acc[r][c] += a[r] * bb[c];
    }
    __syncthreads();
  }

#pragma unroll
  for (int r = 0; r < 4; r++) {
    const int gi = ti * 64 + ty * 4 + r;
#pragma unroll
    for (int c = 0; c < 4; c++) {
      const int gj = tj * 64 + tx * 4 + c;
      if (gi < N_ && gj < N_) {
        Gp[(size_t)gi * GSTRIDE + gj] = acc[r][c];
        if (ti != tj) Gp[(size_t)gj * GSTRIDE + gi] = acc[r][c];
      }
    }
  }
}

// ---------------------------------------------------------------------------
// Kernel E2: sequential FPS using precomputed Gram + fused output writes.
// One block per pair, 256 threads; per step read G row of cand (L2-hot),
// dist = sqrt(max(Gnn - 2Gnc + Gcc, 0)), block argmax. After the 49 tokens
// are fixed, this block writes z rows, token_idx, token_mask (old kF).
// ---------------------------------------------------------------------------
__global__ __launch_bounds__(256) void kE2(const double* __restrict__ G,
                                           const float* __restrict__ mask,
                                           const int* __restrict__ fidxw,
                                           const float* __restrict__ x,
                                           float* __restrict__ out) {
  const int p = blockIdx.x;
  const int b = p >> 3;
  const int fi = fidxw[p];
  const double* Gp = G + (size_t)p * (GSTRIDE * GSTRIDE);
  const float* mrow = mask + (size_t)(b * T_ + fi) * N_;
  const float* X = x + ((size_t)(b * T_ + fi)) * (N_ * D_);
  const int tid = threadIdx.x;
  const bool live = tid < N_;

  __shared__ double gds[N_];
  __shared__ double bvS[4];
  __shared__ int biS[4];
  __shared__ int candS;
  __shared__ int toksS[KT_];

  const int valid = (live && mrow[tid] > 0.5f) ? 1 : 0;
  const double gd = live ? Gp[(size_t)tid * GSTRIDE + tid] : 0.0;
  if (live) gds[tid] = gd;
  __syncthreads();

  auto argmax = [&](double v) -> int {
    double bv = v; int bi = tid;
#pragma unroll
    for (int off = 32; off > 0; off >>= 1) {
      const double ov = __shfl_down(bv, off, 64);
      const int    oi = __shfl_down(bi, off, 64);
      if (ov > bv || (ov == bv && oi < bi)) { bv = ov; bi = oi; }
    }
    const int w = tid >> 6;
    if ((tid & 63) == 0) { bvS[w] = bv; biS[w] = bi; }
    __syncthreads();
    if (tid == 0) {
      double B0 = bvS[0]; int best = biS[0];
      for (int q = 1; q < 4; q++)
        if (bvS[q] > B0) { B0 = bvS[q]; best = biS[q]; }  // waves ordered by idx
      candS = best;
    }
    __syncthreads();
    return candS;
  };

  int cand = argmax((live && valid) ? gd : -INFINITY);
  if (tid == 0) toksS[0] = cand;

  double md = -INFINITY;
  for (int k = 1; k < KT_; k++) {
    const double gdc = gds[cand];
    const double g = live ? Gp[(size_t)cand * GSTRIDE + tid] : 0.0;
    const double dist = sqrt(fmax(gd + gdc - 2.0 * g, 0.0));
    if (live) md = valid ? ((k == 1) ? dist : fmin(md, dist)) : -1.0;
    cand = argmax(md);
    if (tid == 0) toksS[k] = cand;
  }
  __syncthreads();

  // fused epilogue (old kF): token_idx, token_mask, z gather
  if (tid < KT_) {
    const int tok = toksS[tid];
    out[TI_OFF + p * KT_ + tid] = (float)tok;
    out[TM_OFF + (size_t)(b * T_ + fi) * N_ + tok] = 1.0f;
  }
  if (tid < 192) {
    for (int r = 0; r < KT_; r++) {
      const float4 v = *(const float4*)(X + (size_t)toksS[r] * D_ + tid * 4);
      *(float4*)(out + ((size_t)(p * KT_ + r)) * D_ + tid * 4) = v;
    }
  }
}

// ---------------------------------------------------------------------------
extern "C" void kernel_launch(void* const* d_in, const int* in_sizes, int n_in,
                              void* d_out, int out_size, void* d_ws, size_t ws_size,
                              hipStream_t stream) {
  (void)in_sizes; (void)n_in; (void)ws_size; (void)out_size;
  const float* x     = (const float*)d_in[0];
  const float* mask  = (const float*)d_in[1];
  const float* gamma = (const float*)d_in[2];
  const float* beta  = (const float*)d_in[3];
  const float* W1    = (const float*)d_in[4];
  const float* b1    = (const float*)d_in[5];
  const float* W2    = (const float*)d_in[6];
  const float* b2    = (const float*)d_in[7];
  float* out = (float*)d_out;
  char* ws = (char*)d_ws;

  double* scorep = (double*)(ws + WS_SCOREP);
  double* fn64   = (double*)(ws + WS_FN64);
  float*  h32    = (float*)(ws + WS_H32);
  int*    validw = (int*)(ws + WS_VALID);
  int*    fidxw  = (int*)(ws + WS_FIDX);
  double* simG   = (double*)(ws + WS_SIM);
  double* G      = (double*)(ws + WS_G);

  // zero only the token_mask region (everything else is fully overwritten)
  hipMemsetAsync(out + TM_OFF, 0, (size_t)TM_SZ * sizeof(float), stream);

  kA<<<B_ * T_, 256, 0, stream>>>(x, mask, gamma, beta, fn64, h32, validw);
  kS<<<B_ * 4, 256, 0, stream>>>(fn64, simG);
  kB<<<dim3(HIDD_ / 128, (B_ * T_) / 32), 256, 0, stream>>>(h32, W1, b1, W2, scorep);
  kD<<<B_, 256, 0, stream>>>(simG, scorep, validw, b2, fidxw, out + FI_OFF, out + FM_OFF);
  kG<<<B_ * KF_ * 10, 256, 0, stream>>>(x, fidxw, G);
  kE2<<<B_ * KF_, 256, 0, stream>>>(G, mask, fidxw, x, out);
}